// Round 8
// baseline (68.106 us; speedup 1.0000x reference)
//
#include <hip/hip_runtime.h>

// CARAFE upsample, N=2 C=256 H=W=128, K=5 S=2 G=1, f32 in/out.
// R7: SINGLE-WAVE workgroups (64 threads). R6's barrier-free version failed
// (suspected compiler-level LDS reordering without barriers); R5's 4-wave
// lockstep was limited by whole-block barrier drains. Here each block is ONE
// wave owning 1 source row x 64 cols x 16 channels with a private 5x68
// double-buffered LDS tile and a real __syncthreads() per channel: barrier
// semantics guarantee ordering (R5-grade correctness), but with 1 wave/block
// the barrier never waits on other waves -- 8 independent blocks/CU overlap
// each other's stalls. Masks (100/thread) stay register/AGPR-resident.

namespace {
constexpr int N_ = 2, C_ = 256, H_ = 128, W_ = 128;
constexpr int K_ = 5, S_ = 2, PAD_ = 2;
constexpr int SH_ = H_ * S_, SW_ = W_ * S_;          // 256, 256
constexpr int CPB = 16;                              // channels per block
constexpr int TPB = 64;                              // ONE wave per block
constexpr int TW  = 68;                              // tile cols (64 + 2*PAD)
constexpr int TR  = 5;                               // tile rows (K)
constexpr int TSZ = TR * TW;                         // 340 floats per tile
constexpr int NSLOT = (TSZ + 63) / 64;               // 6 staging slots/lane
constexpr int SPATIAL = N_ * H_ * (W_ / 64);         // 512 spatial blocks
typedef float v2f __attribute__((ext_vector_type(2)));
}

__global__ __launch_bounds__(TPB, 2) void carafe_kernel(
    const float* __restrict__ feat,
    const float* __restrict__ masks,
    float* __restrict__ out)
{
    __shared__ float lds[2][TSZ];

    const int lane = threadIdx.x;
    const int sp   = blockIdx.x;
    const int n    = sp >> 8;                 // / (H_*2)
    const int rem  = sp & 255;
    const int h    = rem >> 1;                // source row
    const int wc0  = (rem & 1) << 6;          // source col base (0 or 64)
    const int c0   = blockIdx.y * CPB;

    // ---- staging descriptors (invariant over channels): tile idx -> global
    int  goff[NSLOT];
    bool gval[NSLOT];
#pragma unroll
    for (int s = 0; s < NSLOT; ++s) {
        int idx = s * 64 + lane;              // 0..383, tile has 340
        int r  = idx / TW, cc = idx % TW;
        int gy = h - PAD_ + r, gx = wc0 - PAD_ + cc;
        bool ok = (idx < TSZ) && ((unsigned)gy < (unsigned)H_) && ((unsigned)gx < (unsigned)W_);
        gval[s] = ok;
        goff[s] = ok ? (gy * W_ + gx) : 0;
    }

    // ---- 100 mask weights for this thread's 2x2 output quad (reg/AGPR-resident)
    float m0[25], m1[25], m2[25], m3[25];
    {
        const float* mb = masks + ((size_t)n * 25) * (SH_ * SW_)
                                + (size_t)(S_ * h) * SW_ + S_ * (wc0 + lane);
#pragma unroll
        for (int k = 0; k < 25; ++k) {
            v2f tt = *(const v2f*)(mb + (size_t)k * (SH_ * SW_));
            v2f bb = *(const v2f*)(mb + (size_t)k * (SH_ * SW_) + SW_);
            m0[k] = tt.x; m1[k] = tt.y; m2[k] = bb.x; m3[k] = bb.y;
        }
    }

    const float* fb = feat + ((size_t)n * C_ + c0) * (H_ * W_);
    float*       ob = out + (((size_t)n * C_ + c0) * SH_ + (size_t)(S_ * h)) * SW_
                          + S_ * (wc0 + lane);

    auto issue = [&](int c, float* st) {
        const float* f = fb + (size_t)c * (H_ * W_);
#pragma unroll
        for (int s = 0; s < NSLOT; ++s) st[s] = gval[s] ? f[goff[s]] : 0.f;
    };
    auto land = [&](float* tile, const float* st) {
#pragma unroll
        for (int s = 0; s < NSLOT; ++s) {
            int idx = s * 64 + lane;
            if (idx < TSZ) tile[idx] = st[s];
        }
    };
    auto compute_store = [&](const float* L, int c) {
        float a0 = 0.f, a1 = 0.f, a2 = 0.f, a3 = 0.f;
#pragma unroll
        for (int di = 0; di < K_; ++di) {
            const float* Lr = L + di * TW + lane;
            float f0 = Lr[0], f1 = Lr[1], f2 = Lr[2], f3 = Lr[3], f4 = Lr[4];
            const int kb = di * K_;
            a0 = fmaf(f0, m0[kb + 0], a0);
            a1 = fmaf(f0, m1[kb + 0], a1);
            a2 = fmaf(f0, m2[kb + 0], a2);
            a3 = fmaf(f0, m3[kb + 0], a3);
            a0 = fmaf(f1, m0[kb + 1], a0);
            a1 = fmaf(f1, m1[kb + 1], a1);
            a2 = fmaf(f1, m2[kb + 1], a2);
            a3 = fmaf(f1, m3[kb + 1], a3);
            a0 = fmaf(f2, m0[kb + 2], a0);
            a1 = fmaf(f2, m1[kb + 2], a1);
            a2 = fmaf(f2, m2[kb + 2], a2);
            a3 = fmaf(f2, m3[kb + 2], a3);
            a0 = fmaf(f3, m0[kb + 3], a0);
            a1 = fmaf(f3, m1[kb + 3], a1);
            a2 = fmaf(f3, m2[kb + 3], a2);
            a3 = fmaf(f3, m3[kb + 3], a3);
            a0 = fmaf(f4, m0[kb + 4], a0);
            a1 = fmaf(f4, m1[kb + 4], a1);
            a2 = fmaf(f4, m2[kb + 4], a2);
            a3 = fmaf(f4, m3[kb + 4], a3);
        }
        float* oc = ob + (size_t)c * ((size_t)SH_ * SW_);
        v2f top = {a0, a1}, bot = {a2, a3};
        __builtin_nontemporal_store(top, (v2f*)oc);
        __builtin_nontemporal_store(bot, (v2f*)(oc + SW_));
    };

    // ---- prologue: channel 0 straight into lds[0]
#pragma unroll
    for (int s = 0; s < NSLOT; ++s) {
        int idx = s * 64 + lane;
        if (idx < TSZ) lds[0][idx] = gval[s] ? fb[goff[s]] : 0.f;
    }
    __syncthreads();

    float stA[NSLOT], stB[NSLOT];
    for (int c2 = 0; c2 < CPB; c2 += 2) {
        // even channel: loads for c2+1 fly while computing c2 from lds[0]
        issue(c2 + 1, stA);
        compute_store(&lds[0][0], c2);
        land(&lds[1][0], stA);
        __syncthreads();

        // odd channel: loads for c2+2 fly while computing c2+1 from lds[1]
        if (c2 + 2 < CPB) issue(c2 + 2, stB);
        compute_store(&lds[1][0], c2 + 1);
        if (c2 + 2 < CPB) land(&lds[0][0], stB);
        __syncthreads();
    }
}

extern "C" void kernel_launch(void* const* d_in, const int* in_sizes, int n_in,
                              void* d_out, int out_size, void* d_ws, size_t ws_size,
                              hipStream_t stream) {
    const float* feat  = (const float*)d_in[0];
    const float* masks = (const float*)d_in[1];
    float* out = (float*)d_out;
    dim3 grid(SPATIAL, C_ / CPB);             // (512, 16) = 8192 single-wave blocks
    carafe_kernel<<<grid, dim3(TPB), 0, stream>>>(feat, masks, out);
}